// Round 1
// baseline (259.476 us; speedup 1.0000x reference)
//
#include <hip/hip_runtime.h>

#define TOKENS   16384
#define DIM      256
#define NEMB     1024
#define MT       64     // tokens per block
#define QN       256    // embeddings per quarter (per block)
#define KC       64     // k-chunk staged in LDS
#define NC       64     // embedding chunk staged in LDS

__device__ __forceinline__ unsigned int fsort(float f) {
    // monotonic float -> uint mapping (total order, preserves <)
    unsigned int u = __float_as_uint(f);
    return (u & 0x80000000u) ? ~u : (u | 0x80000000u);
}

// ---------------- e_sq precompute: one wave per embedding row ----------------
__global__ __launch_bounds__(256) void esq_kernel(const float* __restrict__ E,
                                                  float* __restrict__ esq) {
    const int w    = (blockIdx.x * 256 + threadIdx.x) >> 6;  // 0..1023
    const int lane = threadIdx.x & 63;
    const float4 v = reinterpret_cast<const float4*>(E + (size_t)w * DIM)[lane];
    float s = fmaf(v.x, v.x, fmaf(v.y, v.y, fmaf(v.z, v.z, v.w * v.w)));
    #pragma unroll
    for (int off = 32; off > 0; off >>= 1) s += __shfl_down(s, off);
    if (lane == 0) esq[w] = s;
}

// ---------------- main fused GEMM + argmin ----------------
// grid = 1024: blockIdx & 255 -> token tile (64 tokens), blockIdx >> 8 -> embedding quarter
__global__ __launch_bounds__(256, 4) void vq_main(const float* __restrict__ x,
                                                  const float* __restrict__ E,
                                                  const float* __restrict__ esq,
                                                  unsigned long long* __restrict__ keys) {
    __shared__ float xs[KC][MT];   // k-major: xs[k][m]
    __shared__ float es[KC][NC];   // k-major: es[k][n]

    const int t   = threadIdx.x;
    const int ty  = t >> 4;          // 0..15 -> token group (4 rows each)
    const int tx  = t & 15;          // 0..15 -> embedding group (4 cols each)
    const int tb  = blockIdx.x & 255;
    const int qr  = blockIdx.x >> 8;
    const int m0  = tb * MT;
    const int n0q = qr * QN;

    float acc[4][4][4];              // [nc][i][j], nc fully unrolled -> registers
    #pragma unroll
    for (int nc = 0; nc < 4; ++nc)
        #pragma unroll
        for (int i = 0; i < 4; ++i)
            #pragma unroll
            for (int j = 0; j < 4; ++j) acc[nc][i][j] = 0.f;

    const int sm = t >> 2;   // staging row 0..63
    const int sq = t & 3;    // staging quarter-of-row

    for (int kc = 0; kc < DIM / KC; ++kc) {
        const int k0 = kc * KC;
        #pragma unroll
        for (int nc = 0; nc < 4; ++nc) {
            __syncthreads();   // previous tile fully consumed
            if (nc == 0) {
                // stage x chunk (transposed write), once per kc
                #pragma unroll
                for (int i = 0; i < 4; ++i) {
                    const int k4 = sq * 4 + i;
                    const float4 v = *reinterpret_cast<const float4*>(
                        x + (size_t)(m0 + sm) * DIM + k0 + k4 * 4);
                    xs[k4 * 4 + 0][sm] = v.x; xs[k4 * 4 + 1][sm] = v.y;
                    xs[k4 * 4 + 2][sm] = v.z; xs[k4 * 4 + 3][sm] = v.w;
                }
            }
            {
                // stage E chunk (transposed write)
                const int gn = n0q + nc * NC + sm;
                #pragma unroll
                for (int i = 0; i < 4; ++i) {
                    const int k4 = sq * 4 + i;
                    const float4 v = *reinterpret_cast<const float4*>(
                        E + (size_t)gn * DIM + k0 + k4 * 4);
                    es[k4 * 4 + 0][sm] = v.x; es[k4 * 4 + 1][sm] = v.y;
                    es[k4 * 4 + 2][sm] = v.z; es[k4 * 4 + 3][sm] = v.w;
                }
            }
            __syncthreads();
            #pragma unroll 2
            for (int k = 0; k < KC; ++k) {
                // uniform k per iteration -> conflict-free ds_read_b128
                const float4 a = *reinterpret_cast<const float4*>(&xs[k][ty * 4]);
                const float4 b = *reinterpret_cast<const float4*>(&es[k][tx * 4]);
                const float av[4] = {a.x, a.y, a.z, a.w};
                const float bv[4] = {b.x, b.y, b.z, b.w};
                #pragma unroll
                for (int i = 0; i < 4; ++i)
                    #pragma unroll
                    for (int j = 0; j < 4; ++j)
                        acc[nc][i][j] = fmaf(av[i], bv[j], acc[nc][i][j]);
            }
        }
    }

    // per-thread argmin over this thread's 16 columns (x_sq omitted: constant per token)
    float bestd[4];
    int   besti[4];
    #pragma unroll
    for (int i = 0; i < 4; ++i) { bestd[i] = 3.4e38f; besti[i] = 0; }

    #pragma unroll
    for (int nc = 0; nc < 4; ++nc) {
        #pragma unroll
        for (int j = 0; j < 4; ++j) {
            const int n   = n0q + nc * NC + tx * 4 + j;   // ascending within thread
            const float eq = esq[n];
            #pragma unroll
            for (int i = 0; i < 4; ++i) {
                const float d = fmaf(-2.f, acc[nc][i][j], eq);
                if (d < bestd[i]) { bestd[i] = d; besti[i] = n; }  // strict < keeps lowest idx
            }
        }
    }

    // reduce across the 16 tx lanes (xor offsets stay within 16-lane group)
    #pragma unroll
    for (int off = 8; off >= 1; off >>= 1) {
        #pragma unroll
        for (int i = 0; i < 4; ++i) {
            const float od = __shfl_xor(bestd[i], off);
            const int   oi = __shfl_xor(besti[i], off);
            if (od < bestd[i] || (od == bestd[i] && oi < besti[i])) {
                bestd[i] = od; besti[i] = oi;
            }
        }
    }

    if (tx == 0) {
        #pragma unroll
        for (int i = 0; i < 4; ++i) {
            const unsigned long long key =
                ((unsigned long long)fsort(bestd[i]) << 32) | (unsigned int)besti[i];
            atomicMin(&keys[m0 + ty * 4 + i], key);   // device-scope, cross-XCD safe
        }
    }
}

// ---------------- merge quarters + gather + STE write ----------------
__global__ __launch_bounds__(256) void vq_out(const float* __restrict__ x,
                                              const float* __restrict__ E,
                                              const unsigned long long* __restrict__ keys,
                                              float* __restrict__ out) {
    const int w    = (blockIdx.x * 256 + threadIdx.x) >> 6;  // global wave 0..1023
    const int lane = threadIdx.x & 63;
    #pragma unroll 1
    for (int s = 0; s < 16; ++s) {
        const int r   = w * 16 + s;
        const int idx = (int)(keys[r] & 0xFFFFFFFFull);
        const float4 xv = reinterpret_cast<const float4*>(x + (size_t)r * DIM)[lane];
        const float4 ev = reinterpret_cast<const float4*>(E + (size_t)idx * DIM)[lane];
        float4 o;
        o.x = (xv.x + ev.x) - xv.x;   // match numpy's (x + q) - x rounding order
        o.y = (xv.y + ev.y) - xv.y;
        o.z = (xv.z + ev.z) - xv.z;
        o.w = (xv.w + ev.w) - xv.w;
        reinterpret_cast<float4*>(out + (size_t)r * DIM)[lane] = o;
    }
}

extern "C" void kernel_launch(void* const* d_in, const int* in_sizes, int n_in,
                              void* d_out, int out_size, void* d_ws, size_t ws_size,
                              hipStream_t stream) {
    const float* x = (const float*)d_in[0];        // [16,1024,256] fp32
    const float* E = (const float*)d_in[1];        // [1024,256] fp32
    float* out = (float*)d_out;                    // [16,1024,256] fp32

    unsigned long long* keys = (unsigned long long*)d_ws;           // 16384 * 8 B
    float* esq = (float*)((char*)d_ws + TOKENS * sizeof(unsigned long long)); // 4 KB

    // init keys to +max (ws is poisoned 0xAA, which is NOT an identity for our min)
    hipMemsetAsync(keys, 0xFF, TOKENS * sizeof(unsigned long long), stream);

    esq_kernel<<<NEMB * 64 / 256, 256, 0, stream>>>(E, esq);
    vq_main<<<1024, 256, 0, stream>>>(x, E, esq, keys);
    vq_out<<<TOKENS / 16 * 64 / 256, 256, 0, stream>>>(x, E, keys, out);
}

// Round 2
// 207.265 us; speedup vs baseline: 1.2519x; 1.2519x over previous
//
#include <hip/hip_runtime.h>

#define TOKENS   16384
#define DIM      256
#define NEMB     1024
#define MT       128    // tokens per block tile
#define NT       128    // embeddings per block tile
#define KC       32     // k-chunk staged in LDS

__device__ __forceinline__ unsigned int fsort(float f) {
    // monotonic float -> uint mapping (total order, preserves <)
    unsigned int u = __float_as_uint(f);
    return (u & 0x80000000u) ? ~u : (u | 0x80000000u);
}

// ---------------- e_sq precompute: one wave per embedding row ----------------
__global__ __launch_bounds__(256) void esq_kernel(const float* __restrict__ E,
                                                  float* __restrict__ esq) {
    const int w    = (blockIdx.x * 256 + threadIdx.x) >> 6;  // 0..1023
    const int lane = threadIdx.x & 63;
    const float4 v = reinterpret_cast<const float4*>(E + (size_t)w * DIM)[lane];
    float s = fmaf(v.x, v.x, fmaf(v.y, v.y, fmaf(v.z, v.z, v.w * v.w)));
    #pragma unroll
    for (int off = 32; off > 0; off >>= 1) s += __shfl_down(s, off);
    if (lane == 0) esq[w] = s;
}

// ---------------- main fused GEMM + argmin ----------------
// grid = 1024: blockIdx & 127 -> token tile (128 tokens), blockIdx >> 7 -> embed tile (128 embeds)
// 256 threads = 16x16 thread grid, 8x8 micro-tile per thread (rows/cols split 0/64).
__global__ __launch_bounds__(256, 4) void vq_main(const float* __restrict__ x,
                                                  const float* __restrict__ E,
                                                  const float* __restrict__ esq,
                                                  unsigned long long* __restrict__ keys) {
    // k-major, k-XOR-swizzled: element (k,m) lives at [k][m ^ ((k>>2)<<2)]
    __shared__ float xs[KC][MT];
    __shared__ float es[KC][NT];

    const int t  = threadIdx.x;
    const int ty = t >> 4;           // 0..15 -> token rows ty*4 / 64+ty*4
    const int tx = t & 15;           // 0..15 -> embed cols tx*4 / 64+tx*4
    const int m0 = (blockIdx.x & 127) * MT;
    const int n0 = (blockIdx.x >> 7) * NT;

    float acc[8][8];
    #pragma unroll
    for (int i = 0; i < 8; ++i)
        #pragma unroll
        for (int j = 0; j < 8; ++j) acc[i][j] = 0.f;

    const int sc = t & 7;            // staging k-chunk (4 k's each)
    const int sr = t >> 3;           // staging row 0..31 (+32*ii)
    const int sw = sc << 2;          // row-swizzle XOR for this thread's writes

    for (int kc = 0; kc < DIM / KC; ++kc) {
        const int k0 = kc * KC;
        __syncthreads();             // previous tile fully consumed
        #pragma unroll
        for (int ii = 0; ii < 4; ++ii) {
            const int r  = sr + 32 * ii;
            const int rw = r ^ sw;   // swizzled row (bank = (r^4c)%32 -> 2-way, free)
            const float4 vx = *reinterpret_cast<const float4*>(
                x + (size_t)(m0 + r) * DIM + k0 + sc * 4);
            const float4 ve = *reinterpret_cast<const float4*>(
                E + (size_t)(n0 + r) * DIM + k0 + sc * 4);
            xs[sc * 4 + 0][rw] = vx.x; xs[sc * 4 + 1][rw] = vx.y;
            xs[sc * 4 + 2][rw] = vx.z; xs[sc * 4 + 3][rw] = vx.w;
            es[sc * 4 + 0][rw] = ve.x; es[sc * 4 + 1][rw] = ve.y;
            es[sc * 4 + 2][rw] = ve.z; es[sc * 4 + 3][rw] = ve.w;
        }
        __syncthreads();

        #pragma unroll 8
        for (int k = 0; k < KC; ++k) {
            const int v = ((k >> 2) & 7) << 2;   // read-side un-swizzle (const per k)
            const float4 a0 = *reinterpret_cast<const float4*>(&xs[k][(ty * 4) ^ v]);
            const float4 a1 = *reinterpret_cast<const float4*>(&xs[k][(64 + ty * 4) ^ v]);
            const float4 b0 = *reinterpret_cast<const float4*>(&es[k][(tx * 4) ^ v]);
            const float4 b1 = *reinterpret_cast<const float4*>(&es[k][(64 + tx * 4) ^ v]);
            const float a[8] = {a0.x, a0.y, a0.z, a0.w, a1.x, a1.y, a1.z, a1.w};
            const float b[8] = {b0.x, b0.y, b0.z, b0.w, b1.x, b1.y, b1.z, b1.w};
            #pragma unroll
            for (int i = 0; i < 8; ++i)
                #pragma unroll
                for (int j = 0; j < 8; ++j)
                    acc[i][j] = fmaf(a[i], b[j], acc[i][j]);
        }
    }

    // per-thread argmin over this thread's 8 cols, per row (x_sq omitted: const per token)
    float bd[8];
    int   bi[8];
    #pragma unroll
    for (int i = 0; i < 8; ++i) { bd[i] = 3.4e38f; bi[i] = 0; }

    #pragma unroll
    for (int j = 0; j < 8; ++j) {                 // ascending n within thread
        const int n   = n0 + (j >> 2) * 64 + tx * 4 + (j & 3);
        const float eq = esq[n];
        #pragma unroll
        for (int i = 0; i < 8; ++i) {
            const float d = fmaf(-2.f, acc[i][j], eq);
            if (d < bd[i]) { bd[i] = d; bi[i] = n; }   // strict < keeps lowest idx
        }
    }

    // reduce across the 16 tx lanes (xor offsets stay within the 16-lane tx group)
    #pragma unroll
    for (int off = 8; off >= 1; off >>= 1) {
        #pragma unroll
        for (int i = 0; i < 8; ++i) {
            const float od = __shfl_xor(bd[i], off);
            const int   oi = __shfl_xor(bi[i], off);
            if (od < bd[i] || (od == bd[i] && oi < bi[i])) { bd[i] = od; bi[i] = oi; }
        }
    }

    if (tx == 0) {
        #pragma unroll
        for (int i = 0; i < 8; ++i) {
            const int row = m0 + (i >> 2) * 64 + ty * 4 + (i & 3);
            const unsigned long long key =
                ((unsigned long long)fsort(bd[i]) << 32) | (unsigned int)bi[i];
            atomicMin(&keys[row], key);   // device-scope, cross-XCD safe
        }
    }
}

// ---------------- merge tiles + gather + STE write ----------------
__global__ __launch_bounds__(256) void vq_out(const float* __restrict__ x,
                                              const float* __restrict__ E,
                                              const unsigned long long* __restrict__ keys,
                                              float* __restrict__ out) {
    const int w    = (blockIdx.x * 256 + threadIdx.x) >> 6;  // global wave 0..1023
    const int lane = threadIdx.x & 63;
    #pragma unroll 1
    for (int s = 0; s < 16; ++s) {
        const int r   = w * 16 + s;
        const int idx = (int)(keys[r] & 0xFFFFFFFFull);
        const float4 xv = reinterpret_cast<const float4*>(x + (size_t)r * DIM)[lane];
        const float4 ev = reinterpret_cast<const float4*>(E + (size_t)idx * DIM)[lane];
        float4 o;
        o.x = (xv.x + ev.x) - xv.x;   // match numpy's (x + q) - x rounding order
        o.y = (xv.y + ev.y) - xv.y;
        o.z = (xv.z + ev.z) - xv.z;
        o.w = (xv.w + ev.w) - xv.w;
        reinterpret_cast<float4*>(out + (size_t)r * DIM)[lane] = o;
    }
}

extern "C" void kernel_launch(void* const* d_in, const int* in_sizes, int n_in,
                              void* d_out, int out_size, void* d_ws, size_t ws_size,
                              hipStream_t stream) {
    const float* x = (const float*)d_in[0];        // [16,1024,256] fp32
    const float* E = (const float*)d_in[1];        // [1024,256] fp32
    float* out = (float*)d_out;                    // [16,1024,256] fp32

    unsigned long long* keys = (unsigned long long*)d_ws;                         // 128 KB
    float* esq = (float*)((char*)d_ws + TOKENS * sizeof(unsigned long long));     // 4 KB

    // init keys to +max (ws is poisoned 0xAA, which is NOT an identity for our min)
    hipMemsetAsync(keys, 0xFF, TOKENS * sizeof(unsigned long long), stream);

    esq_kernel<<<NEMB * 64 / 256, 256, 0, stream>>>(E, esq);
    vq_main<<<1024, 256, 0, stream>>>(x, E, esq, keys);
    vq_out<<<TOKENS / 16 * 64 / 256, 256, 0, stream>>>(x, E, keys, out);
}

// Round 3
// 127.314 us; speedup vs baseline: 2.0381x; 1.6280x over previous
//
#include <hip/hip_runtime.h>

#define TOKENS 16384
#define DIM    256
#define NEMB   1024
#define KB2    512     // bf16 K per matrix: [hi 0..255 | lo 256..511]
#define MT     128     // token tile
#define NT     128     // embed tile
#define NSTEP  12      // 3-term split-GEMM: K=768 in steps of 64

typedef __attribute__((ext_vector_type(8))) short short8;
typedef __attribute__((ext_vector_type(4))) float f32x4;

__device__ __forceinline__ unsigned int fsort(float f) {
    unsigned int u = __float_as_uint(f);
    return (u & 0x80000000u) ? ~u : (u | 0x80000000u);
}
__device__ __forceinline__ unsigned short bf16_rn(float f) {
    unsigned int u = __float_as_uint(f);
    u += 0x7fff + ((u >> 16) & 1);
    return (unsigned short)(u >> 16);
}
__device__ __forceinline__ float bf16_to_f(unsigned short h) {
    unsigned int u = (unsigned int)h << 16;
    return __uint_as_float(u);
}

// ---------------- prep: split x,E into bf16 hi/lo pairs; exact fp32 esq ----------------
// rows 0..TOKENS-1 -> xbf, rows TOKENS.. -> ebf (+esq). One wave per row-group of 4.
__global__ __launch_bounds__(256) void prep_kernel(const float* __restrict__ x,
                                                   const float* __restrict__ E,
                                                   unsigned short* __restrict__ xbf,
                                                   unsigned short* __restrict__ ebf,
                                                   float* __restrict__ esq) {
    const int wave = (blockIdx.x * 256 + threadIdx.x) >> 6;
    const int lane = threadIdx.x & 63;
    #pragma unroll 1
    for (int rr = 0; rr < 4; ++rr) {
        const int row = wave * 4 + rr;                       // 0..17407, wave-uniform
        const bool isE = row >= TOKENS;
        const float* src = isE ? (E + (size_t)(row - TOKENS) * DIM)
                               : (x + (size_t)row * DIM);
        const float4 v = reinterpret_cast<const float4*>(src)[lane];
        const float f[4] = {v.x, v.y, v.z, v.w};
        unsigned long long hv = 0, lv = 0;
        #pragma unroll
        for (int i = 0; i < 4; ++i) {
            const unsigned short h = bf16_rn(f[i]);
            const float r = f[i] - bf16_to_f(h);             // exact (Sterbenz)
            const unsigned short l = bf16_rn(r);
            hv |= (unsigned long long)h << (16 * i);
            lv |= (unsigned long long)l << (16 * i);
        }
        unsigned short* dst = isE ? (ebf + (size_t)(row - TOKENS) * KB2)
                                  : (xbf + (size_t)row * KB2);
        *reinterpret_cast<unsigned long long*>(dst + 4 * lane)       = hv;
        *reinterpret_cast<unsigned long long*>(dst + 256 + 4 * lane) = lv;
        if (isE) {
            float s = fmaf(v.x, v.x, fmaf(v.y, v.y, fmaf(v.z, v.z, v.w * v.w)));
            #pragma unroll
            for (int off = 32; off > 0; off >>= 1) s += __shfl_down(s, off);
            if (lane == 0) esq[row - TOKENS] = s;
        }
    }
}

// ---------------- MFMA split-GEMM + fused argmin ----------------
// grid 1024: blockIdx&127 -> token tile, blockIdx>>7 -> embed tile.
// 256 thr = 4 waves (2x2), wave tile 64x64 = 4x4 frags of 16x16x32 bf16 MFMA.
__global__ __launch_bounds__(256) void vq_mfma(const unsigned short* __restrict__ xbf,
                                               const unsigned short* __restrict__ ebf,
                                               const float* __restrict__ esq,
                                               unsigned long long* __restrict__ keys) {
    __shared__ unsigned short Als[MT * 64];   // [row][64k] linear, source pre-swizzled
    __shared__ unsigned short Bls[NT * 64];

    const int t    = threadIdx.x;
    const int lane = t & 63;
    const int w    = t >> 6;             // wave 0..3
    const int wr   = w >> 1, wc = w & 1;
    const int m0   = (int)(blockIdx.x & 127) * MT;
    const int n0   = (int)(blockIdx.x >> 7) * NT;

    f32x4 acc[4][4];
    #pragma unroll
    for (int i = 0; i < 4; ++i)
        #pragma unroll
        for (int j = 0; j < 4; ++j) acc[i][j] = (f32x4){0.f, 0.f, 0.f, 0.f};

    const int srow   = lane >> 3;                 // row within 8-row staging group
    const int schunk = (lane & 7) ^ srow;         // pre-swizzled 16B chunk of the 128B row

    for (int s = 0; s < NSTEP; ++s) {
        // K-step source chunk (of 64 bf16) in the [hi|lo] layout:
        // A: hi,hi,lo  B: hi,lo,hi (3-term split product)
        const int ksA = (s < 4) ? s : (s - 4);
        const int ksB = (s < 4) ? s : ((s < 8) ? s : (s - 8));
        __syncthreads();   // previous tile fully consumed
        #pragma unroll
        for (int c = 0; c < 4; ++c) {
            const int ra = m0 + w * 32 + c * 8 + srow;
            const int rb = n0 + w * 32 + c * 8 + srow;
            const char* ga = (const char*)(xbf + (size_t)ra * KB2 + ksA * 64) + schunk * 16;
            const char* gb = (const char*)(ebf + (size_t)rb * KB2 + ksB * 64) + schunk * 16;
            __builtin_amdgcn_global_load_lds(
                (const __attribute__((address_space(1))) unsigned int*)ga,
                (__attribute__((address_space(3))) unsigned int*)((char*)Als + (w * 32 + c * 8) * 128),
                16, 0, 0);
            __builtin_amdgcn_global_load_lds(
                (const __attribute__((address_space(1))) unsigned int*)gb,
                (__attribute__((address_space(3))) unsigned int*)((char*)Bls + (w * 32 + c * 8) * 128),
                16, 0, 0);
        }
        __syncthreads();   // compiler drains vmcnt before barrier

        const int rA = lane & 15;
        const int g  = lane >> 4;
        #pragma unroll
        for (int kh = 0; kh < 2; ++kh) {
            short8 af[4], bfr[4];
            #pragma unroll
            for (int mf = 0; mf < 4; ++mf) {
                const int row = wr * 64 + mf * 16 + rA;
                const int ch  = (kh * 4 + g) ^ (row & 7);    // read-side un-swizzle
                af[mf] = *(const short8*)((const char*)Als + row * 128 + ch * 16);
            }
            #pragma unroll
            for (int nf = 0; nf < 4; ++nf) {
                const int row = wc * 64 + nf * 16 + rA;
                const int ch  = (kh * 4 + g) ^ (row & 7);
                bfr[nf] = *(const short8*)((const char*)Bls + row * 128 + ch * 16);
            }
            #pragma unroll
            for (int mf = 0; mf < 4; ++mf)
                #pragma unroll
                for (int nf = 0; nf < 4; ++nf)
                    acc[mf][nf] = __builtin_amdgcn_mfma_f32_16x16x32_bf16(
                        af[mf], bfr[nf], acc[mf][nf], 0, 0, 0);
        }
    }

    // fused argmin epilogue: d2 = esq[n] - 2*dot (x_sq const per token, dropped)
    const int g  = lane >> 4;    // C/D: col = lane&15, row = g*4 + reg
    const int cl = lane & 15;
    float bd[4][4];
    int   bi[4][4];
    #pragma unroll
    for (int mf = 0; mf < 4; ++mf)
        #pragma unroll
        for (int j = 0; j < 4; ++j) { bd[mf][j] = 3.4e38f; bi[mf][j] = 0; }

    #pragma unroll
    for (int nf = 0; nf < 4; ++nf) {       // ascending n within lane
        const int n    = n0 + wc * 64 + nf * 16 + cl;
        const float eq = esq[n];
        #pragma unroll
        for (int mf = 0; mf < 4; ++mf)
            #pragma unroll
            for (int j = 0; j < 4; ++j) {
                const float d = fmaf(-2.f, acc[mf][nf][j], eq);
                if (d < bd[mf][j]) { bd[mf][j] = d; bi[mf][j] = n; }  // strict <
            }
    }

    #pragma unroll
    for (int off = 8; off >= 1; off >>= 1) {   // reduce across the 16 cl lanes
        #pragma unroll
        for (int mf = 0; mf < 4; ++mf)
            #pragma unroll
            for (int j = 0; j < 4; ++j) {
                const float od = __shfl_xor(bd[mf][j], off);
                const int   oi = __shfl_xor(bi[mf][j], off);
                if (od < bd[mf][j] || (od == bd[mf][j] && oi < bi[mf][j])) {
                    bd[mf][j] = od; bi[mf][j] = oi;
                }
            }
    }

    if (cl == 0) {
        #pragma unroll
        for (int mf = 0; mf < 4; ++mf)
            #pragma unroll
            for (int j = 0; j < 4; ++j) {
                const int row = m0 + wr * 64 + mf * 16 + g * 4 + j;
                const unsigned long long key =
                    ((unsigned long long)fsort(bd[mf][j]) << 32) | (unsigned int)bi[mf][j];
                atomicMin(&keys[row], key);
            }
    }
}

// ---------------- merge tiles + gather + STE write ----------------
__global__ __launch_bounds__(256) void vq_out(const float* __restrict__ x,
                                              const float* __restrict__ E,
                                              const unsigned long long* __restrict__ keys,
                                              float* __restrict__ out) {
    const int w    = (blockIdx.x * 256 + threadIdx.x) >> 6;
    const int lane = threadIdx.x & 63;
    #pragma unroll 1
    for (int s = 0; s < 16; ++s) {
        const int r   = w * 16 + s;
        const int idx = (int)(keys[r] & 0xFFFFFFFFull);
        const float4 xv = reinterpret_cast<const float4*>(x + (size_t)r * DIM)[lane];
        const float4 ev = reinterpret_cast<const float4*>(E + (size_t)idx * DIM)[lane];
        float4 o;
        o.x = (xv.x + ev.x) - xv.x;   // match numpy's (x + q) - x rounding order
        o.y = (xv.y + ev.y) - xv.y;
        o.z = (xv.z + ev.z) - xv.z;
        o.w = (xv.w + ev.w) - xv.w;
        reinterpret_cast<float4*>(out + (size_t)r * DIM)[lane] = o;
    }
}

extern "C" void kernel_launch(void* const* d_in, const int* in_sizes, int n_in,
                              void* d_out, int out_size, void* d_ws, size_t ws_size,
                              hipStream_t stream) {
    const float* x = (const float*)d_in[0];    // [16,1024,256] fp32
    const float* E = (const float*)d_in[1];    // [1024,256] fp32
    float* out = (float*)d_out;

    // ws layout: keys 128KB | esq 4KB | ebf 1MB  (= 1.16 MB total)
    unsigned long long* keys = (unsigned long long*)d_ws;
    float* esq = (float*)((char*)d_ws + TOKENS * sizeof(unsigned long long));
    unsigned short* ebf = (unsigned short*)((char*)d_ws + TOKENS * 8 + 4096);
    // x split lives in d_out: 16384*512*2 B == out bytes exactly; fully
    // consumed by vq_mfma before vq_out overwrites d_out with the result.
    unsigned short* xbf = (unsigned short*)d_out;

    hipMemsetAsync(keys, 0xFF, TOKENS * sizeof(unsigned long long), stream);
    prep_kernel<<<(TOKENS + NEMB) / 16, 256, 0, stream>>>(x, E, xbf, ebf, esq);
    vq_mfma<<<1024, 256, 0, stream>>>(xbf, ebf, esq, keys);
    vq_out<<<TOKENS / 16 * 64 / 256, 256, 0, stream>>>(x, E, keys, out);
}

// Round 4
// 123.902 us; speedup vs baseline: 2.0942x; 1.0275x over previous
//
#include <hip/hip_runtime.h>

#define TOKENS 16384
#define DIM    256
#define NEMB   1024
#define KB2    512     // bf16 K per matrix: [hi 0..255 | lo 256..511]
#define MT     128     // token tile
#define NT     128     // embed tile
#define NSTEP  12      // 3-term split-GEMM: K=768 in steps of 64

typedef __attribute__((ext_vector_type(8))) short short8;
typedef __attribute__((ext_vector_type(4))) float f32x4;

__device__ __forceinline__ unsigned int fsort(float f) {
    unsigned int u = __float_as_uint(f);
    return (u & 0x80000000u) ? ~u : (u | 0x80000000u);
}
__device__ __forceinline__ unsigned short bf16_rn(float f) {
    unsigned int u = __float_as_uint(f);
    u += 0x7fff + ((u >> 16) & 1);
    return (unsigned short)(u >> 16);
}
__device__ __forceinline__ float bf16_to_f(unsigned short h) {
    unsigned int u = (unsigned int)h << 16;
    return __uint_as_float(u);
}

// ---------------- prep: split x,E into bf16 hi/lo pairs; exact fp32 esq ----------------
__global__ __launch_bounds__(256) void prep_kernel(const float* __restrict__ x,
                                                   const float* __restrict__ E,
                                                   unsigned short* __restrict__ xbf,
                                                   unsigned short* __restrict__ ebf,
                                                   float* __restrict__ esq) {
    const int wave = (blockIdx.x * 256 + threadIdx.x) >> 6;
    const int lane = threadIdx.x & 63;
    #pragma unroll 1
    for (int rr = 0; rr < 4; ++rr) {
        const int row = wave * 4 + rr;                       // 0..17407, wave-uniform
        const bool isE = row >= TOKENS;
        const float* src = isE ? (E + (size_t)(row - TOKENS) * DIM)
                               : (x + (size_t)row * DIM);
        const float4 v = reinterpret_cast<const float4*>(src)[lane];
        const float f[4] = {v.x, v.y, v.z, v.w};
        unsigned long long hv = 0, lv = 0;
        #pragma unroll
        for (int i = 0; i < 4; ++i) {
            const unsigned short h = bf16_rn(f[i]);
            const float r = f[i] - bf16_to_f(h);             // exact (Sterbenz)
            const unsigned short l = bf16_rn(r);
            hv |= (unsigned long long)h << (16 * i);
            lv |= (unsigned long long)l << (16 * i);
        }
        unsigned short* dst = isE ? (ebf + (size_t)(row - TOKENS) * KB2)
                                  : (xbf + (size_t)row * KB2);
        *reinterpret_cast<unsigned long long*>(dst + 4 * lane)       = hv;
        *reinterpret_cast<unsigned long long*>(dst + 256 + 4 * lane) = lv;
        if (isE) {
            float s = fmaf(v.x, v.x, fmaf(v.y, v.y, fmaf(v.z, v.z, v.w * v.w)));
            #pragma unroll
            for (int off = 32; off > 0; off >>= 1) s += __shfl_down(s, off);
            if (lane == 0) esq[row - TOKENS] = s;
        }
    }
}

// ---------------- MFMA split-GEMM + fused argmin, 2-phase double-buffered ----------------
// grid 1024, XCD-swizzled: each XCD owns one embed tile (B panel L2-hot).
// 256 thr = 4 waves (2x2), wave tile 64x64 = 4x4 frags of 16x16x32 bf16 MFMA.
__global__ __launch_bounds__(256) void vq_mfma(const unsigned short* __restrict__ xbf,
                                               const unsigned short* __restrict__ ebf,
                                               const float* __restrict__ esq,
                                               unsigned long long* __restrict__ keys) {
    __shared__ unsigned short ls[2][(MT + NT) * 64];   // 2 x 32KB double buffer

    const int t    = threadIdx.x;
    const int lane = t & 63;
    const int w    = t >> 6;             // wave 0..3
    const int wr   = w >> 1, wc = w & 1;
    // T1 XCD swizzle (1024 % 8 == 0, bijective): XCD k gets logical blocks k*128..k*128+127,
    // which all share the same embed tile -> B panel stays hot in that XCD's L2.
    const int bid  = (int)blockIdx.x;
    const int lb   = (bid & 7) * 128 + (bid >> 3);
    const int m0   = (lb & 127) * MT;
    const int n0   = (lb >> 7) * NT;

    f32x4 acc[4][4];
    #pragma unroll
    for (int i = 0; i < 4; ++i)
        #pragma unroll
        for (int j = 0; j < 4; ++j) acc[i][j] = (f32x4){0.f, 0.f, 0.f, 0.f};

    const int srow   = lane >> 3;                 // row within 8-row staging group
    const int schunk = (lane & 7) ^ srow;         // pre-swizzled 16B chunk of the 128B row

    // stage K-step s into LDS buffer at lbase (A rows 0..127, B rows 128..255)
    auto stage = [&](char* lbase, int s) {
        // A: hi,hi,lo   B: hi,lo,hi (3-term split product)
        const int ksA = (s < 4) ? s : (s - 4);
        const int ksB = (s < 8) ? s : (s - 8);
        #pragma unroll
        for (int c = 0; c < 4; ++c) {
            const int ra = m0 + w * 32 + c * 8 + srow;
            const int rb = n0 + w * 32 + c * 8 + srow;
            const char* ga = (const char*)(xbf + (size_t)ra * KB2 + ksA * 64) + schunk * 16;
            const char* gb = (const char*)(ebf + (size_t)rb * KB2 + ksB * 64) + schunk * 16;
            __builtin_amdgcn_global_load_lds(
                (const __attribute__((address_space(1))) unsigned int*)ga,
                (__attribute__((address_space(3))) unsigned int*)(lbase + (w * 32 + c * 8) * 128),
                16, 0, 0);
            __builtin_amdgcn_global_load_lds(
                (const __attribute__((address_space(1))) unsigned int*)gb,
                (__attribute__((address_space(3))) unsigned int*)(lbase + (MT + w * 32 + c * 8) * 128),
                16, 0, 0);
        }
    };

    auto compute = [&](const char* lbase) {
        const int rA = lane & 15;
        const int g  = lane >> 4;
        #pragma unroll
        for (int kh = 0; kh < 2; ++kh) {
            short8 af[4], bfr[4];
            #pragma unroll
            for (int mf = 0; mf < 4; ++mf) {
                const int row = wr * 64 + mf * 16 + rA;
                const int ch  = (kh * 4 + g) ^ (row & 7);    // read-side un-swizzle
                af[mf] = *(const short8*)(lbase + row * 128 + ch * 16);
            }
            #pragma unroll
            for (int nf = 0; nf < 4; ++nf) {
                const int row = wc * 64 + nf * 16 + rA;
                const int ch  = (kh * 4 + g) ^ (row & 7);
                bfr[nf] = *(const short8*)(lbase + (MT + row) * 128 + ch * 16);
            }
            #pragma unroll
            for (int mf = 0; mf < 4; ++mf)
                #pragma unroll
                for (int nf = 0; nf < 4; ++nf)
                    acc[mf][nf] = __builtin_amdgcn_mfma_f32_16x16x32_bf16(
                        af[mf], bfr[nf], acc[mf][nf], 0, 0, 0);
        }
    };

    // 2-phase pipeline: issue next-tile loads BEFORE computing current tile;
    // one barrier per tile (its implicit vmcnt(0) drain lands after compute).
    stage((char*)ls[0], 0);
    __syncthreads();
    #pragma unroll 1
    for (int sp = 0; sp < NSTEP; sp += 2) {
        stage((char*)ls[1], sp + 1);
        compute((char*)ls[0]);
        __syncthreads();
        if (sp < NSTEP - 2) stage((char*)ls[0], sp + 2);
        compute((char*)ls[1]);
        __syncthreads();
    }

    // fused argmin epilogue: d2 = esq[n] - 2*dot (x_sq const per token, dropped)
    const int g  = lane >> 4;    // C/D: col = lane&15, row = g*4 + reg
    const int cl = lane & 15;
    float bd[4][4];
    int   bi[4][4];
    #pragma unroll
    for (int mf = 0; mf < 4; ++mf)
        #pragma unroll
        for (int j = 0; j < 4; ++j) { bd[mf][j] = 3.4e38f; bi[mf][j] = 0; }

    #pragma unroll
    for (int nf = 0; nf < 4; ++nf) {       // ascending n within lane
        const int n    = n0 + wc * 64 + nf * 16 + cl;
        const float eq = esq[n];
        #pragma unroll
        for (int mf = 0; mf < 4; ++mf)
            #pragma unroll
            for (int j = 0; j < 4; ++j) {
                const float d = fmaf(-2.f, acc[mf][nf][j], eq);
                if (d < bd[mf][j]) { bd[mf][j] = d; bi[mf][j] = n; }  // strict <
            }
    }

    #pragma unroll
    for (int off = 8; off >= 1; off >>= 1) {   // reduce across the 16 cl lanes
        #pragma unroll
        for (int mf = 0; mf < 4; ++mf)
            #pragma unroll
            for (int j = 0; j < 4; ++j) {
                const float od = __shfl_xor(bd[mf][j], off);
                const int   oi = __shfl_xor(bi[mf][j], off);
                if (od < bd[mf][j] || (od == bd[mf][j] && oi < bi[mf][j])) {
                    bd[mf][j] = od; bi[mf][j] = oi;
                }
            }
    }

    if (cl == 0) {
        #pragma unroll
        for (int mf = 0; mf < 4; ++mf)
            #pragma unroll
            for (int j = 0; j < 4; ++j) {
                const int row = m0 + wr * 64 + mf * 16 + g * 4 + j;
                const unsigned long long key =
                    ((unsigned long long)fsort(bd[mf][j]) << 32) | (unsigned int)bi[mf][j];
                atomicMin(&keys[row], key);
            }
    }
}

// ---------------- merge tiles + gather + STE write ----------------
// 1024 blocks; each wave owns 4 rows, all loads issued up-front (8 in flight).
__global__ __launch_bounds__(256) void vq_out(const float* __restrict__ x,
                                              const float* __restrict__ E,
                                              const unsigned long long* __restrict__ keys,
                                              float* __restrict__ out) {
    const int wave = (blockIdx.x * 256 + threadIdx.x) >> 6;  // 0..4095
    const int lane = threadIdx.x & 63;
    const int r0   = wave * 4;
    int idx[4];
    #pragma unroll
    for (int i = 0; i < 4; ++i) idx[i] = (int)(keys[r0 + i] & 0xFFFFFFFFull);
    float4 xv[4], ev[4];
    #pragma unroll
    for (int i = 0; i < 4; ++i)
        xv[i] = reinterpret_cast<const float4*>(x + (size_t)(r0 + i) * DIM)[lane];
    #pragma unroll
    for (int i = 0; i < 4; ++i)
        ev[i] = reinterpret_cast<const float4*>(E + (size_t)idx[i] * DIM)[lane];
    #pragma unroll
    for (int i = 0; i < 4; ++i) {
        float4 o;
        o.x = (xv[i].x + ev[i].x) - xv[i].x;   // match numpy's (x + q) - x rounding order
        o.y = (xv[i].y + ev[i].y) - xv[i].y;
        o.z = (xv[i].z + ev[i].z) - xv[i].z;
        o.w = (xv[i].w + ev[i].w) - xv[i].w;
        reinterpret_cast<float4*>(out + (size_t)(r0 + i) * DIM)[lane] = o;
    }
}

extern "C" void kernel_launch(void* const* d_in, const int* in_sizes, int n_in,
                              void* d_out, int out_size, void* d_ws, size_t ws_size,
                              hipStream_t stream) {
    const float* x = (const float*)d_in[0];    // [16,1024,256] fp32
    const float* E = (const float*)d_in[1];    // [1024,256] fp32
    float* out = (float*)d_out;

    // ws layout: keys 128KB | esq 4KB | ebf 1MB
    unsigned long long* keys = (unsigned long long*)d_ws;
    float* esq = (float*)((char*)d_ws + TOKENS * sizeof(unsigned long long));
    unsigned short* ebf = (unsigned short*)((char*)d_ws + TOKENS * 8 + 4096);
    // x split lives in d_out (exact size match); fully consumed by vq_mfma
    // before vq_out overwrites d_out with the result.
    unsigned short* xbf = (unsigned short*)d_out;

    hipMemsetAsync(keys, 0xFF, TOKENS * sizeof(unsigned long long), stream);
    prep_kernel<<<(TOKENS + NEMB) / 16, 256, 0, stream>>>(x, E, xbf, ebf, esq);
    vq_mfma<<<1024, 256, 0, stream>>>(xbf, ebf, esq, keys);
    vq_out<<<TOKENS / 4 / 4, 256, 0, stream>>>(x, E, keys, out);
}